// Round 20
// baseline (213.277 us; speedup 1.0000x reference)
//
#include <hip/hip_runtime.h>

// Problem constants (fixed by setup_inputs):
//   a_arc, s_arc : [64, 1024, 1024] f32
//   adds, pos    : [64, 1024] int32 in [0, 50)
constexpr int NPOS  = 50;
constexpr int NBINS = NPOS * NPOS;   // 2500
constexpr int SL    = 1024;
constexpr int BZ    = 64;
constexpr float ALPHA = 0.3f;

using f32x4  = __attribute__((ext_vector_type(4))) float;
using bf16x8 = __attribute__((ext_vector_type(8))) short;

// ---------------- hist (MFMA, LDS-staged) config ----------------
constexpr int H_THREADS = 256;                  // 4 waves; wave w owns q-tile w
constexpr int ROWS_PB   = 16;                   // rows per block (one M-tile)
constexpr int H_BLOCKS  = BZ * (SL / ROWS_PB);  // 4096
constexpr int KSTEPS    = SL / 32;              // 32
constexpr int APAD      = 1032;                 // row stride in LDS (pad 8)

// ---------------- efrag config (layout: [b][ks][qt][lane] uint4) ----------
constexpr int E_THREADS = 256;
constexpr int E_BLOCKS  = (BZ * KSTEPS * 64) / E_THREADS;   // 512

// ---------------- apply config (R16 verbatim) ----------------
constexpr int A_THREADS      = 256;
constexpr int ROWS_PER_BLOCK = 32;
constexpr int BLOCKS_PER_B   = SL / ROWS_PER_BLOCK;   // 32
constexpr int A_BLOCKS       = BZ * BLOCKS_PER_B;     // 2048

// ---------------------------------------------------------------------------
// Kernel 0: prebuilt one-hot E fragments (R9-verified mapping), relaid as
// [b][ks][qt][lane] so each wave's per-K-step fragment read is 1KB coalesced.
// ---------------------------------------------------------------------------
__global__ __launch_bounds__(E_THREADS) void efrag_kernel(
    const int* __restrict__ adds, uint4* __restrict__ efrag) {
  const int gid  = blockIdx.x * E_THREADS + threadIdx.x;  // (b*32+ks)*64+lane
  const int lane = gid & 63;
  const int ksg  = gid >> 6;
  const int ks   = ksg & 31;
  const int b    = ksg >> 5;
  const int kg   = lane >> 4, l15 = lane & 15;
  const int j    = ks * 32 + kg * 8;

  const int* __restrict__ ap = adds + (size_t)b * SL + j;
  int av[8];
  #pragma unroll
  for (int e = 0; e < 8; ++e) av[e] = ap[e];

  #pragma unroll
  for (int qt = 0; qt < 4; ++qt) {
    const int q = qt * 16 + l15;
    unsigned w[4];
    #pragma unroll
    for (int u = 0; u < 4; ++u) {
      const unsigned lo = (av[2 * u]     == q) ? 0x3F80u : 0u;
      const unsigned hi = (av[2 * u + 1] == q) ? 0x3F80u : 0u;
      w[u] = lo | (hi << 16);
    }
    efrag[((size_t)(b * 32 + ks) * 4 + qt) * 64 + lane] = uint4{w[0], w[1], w[2], w[3]};
  }
}

// ---------------------------------------------------------------------------
// Kernel 1: T[row][q] = sum_j A[row][j]*(adds[j]==q) via MFMA, with A staged
// through LDS from CONTIGUOUS 64KB row-blocks (apply-style streaming — every
// scattered/partial-row variant pinned at 2.7-3.7 TB/s; contiguous gets 6+).
// MFMA math, hi/lo split, fragment semantics identical to R9 (verified).
// ---------------------------------------------------------------------------
__global__ __launch_bounds__(H_THREADS) void hist_mfma(
    const float* __restrict__ a, const uint4* __restrict__ efrag,
    float* __restrict__ tdump) {
  __shared__ float As[ROWS_PB][APAD];    // 66 KB, +8 pad: A-frag reads spread banks
  __shared__ float T_lds[ROWS_PB][66];   // 4.2 KB

  const int tid  = threadIdx.x;
  const int b    = blockIdx.x >> 6;      // 64 row-groups per batch
  const int rg   = blockIdx.x & 63;
  const int row0 = rg * ROWS_PB;

  // --- stage 16 full rows (64KB contiguous), NT, two 8-row passes ---
  {
    const f32x4* __restrict__ src =
        (const f32x4*)(a + ((size_t)b * SL + row0) * SL);
    f32x4 v[8];
    #pragma unroll
    for (int r = 0; r < 8; ++r)
      v[r] = __builtin_nontemporal_load(src + (size_t)r * (SL / 4) + tid);
    #pragma unroll
    for (int r = 0; r < 8; ++r) *(f32x4*)&As[r][4 * tid] = v[r];
    #pragma unroll
    for (int r = 0; r < 8; ++r)
      v[r] = __builtin_nontemporal_load(src + (size_t)(r + 8) * (SL / 4) + tid);
    #pragma unroll
    for (int r = 0; r < 8; ++r) *(f32x4*)&As[r + 8][4 * tid] = v[r];
  }
  __syncthreads();

  // --- K-loop: wave w owns q-tile w; A-frags from LDS; E-frags from global ---
  const int wid = tid >> 6, lane = tid & 63;
  const int kg = lane >> 4, l15 = lane & 15;
  const uint4* __restrict__ Eb =
      efrag + ((size_t)b * KSTEPS * 4 + wid) * 64 + lane;

  f32x4 acc = {0, 0, 0, 0};
  for (int ks0 = 0; ks0 < KSTEPS; ks0 += 4) {
    uint4 e4[4];
    #pragma unroll
    for (int j2 = 0; j2 < 4; ++j2)                 // 4 L2 loads in flight
      e4[j2] = Eb[(size_t)(ks0 + j2) * 256];
    #pragma unroll
    for (int j2 = 0; j2 < 4; ++j2) {
      const int ks = ks0 + j2;
      const f32x4 f0 = *(const f32x4*)&As[l15][ks * 32 + kg * 8];
      const f32x4 f1 = *(const f32x4*)&As[l15][ks * 32 + kg * 8 + 4];
      const float f[8] = {f0[0], f0[1], f0[2], f0[3], f1[0], f1[1], f1[2], f1[3]};
      bf16x8 ah, al;
      #pragma unroll
      for (int e = 0; e < 8; ++e) {                // R9-verified hi/lo split
        const unsigned u = __builtin_bit_cast(unsigned, f[e]);
        ah[e] = (short)(u >> 16);
        const float hf = __builtin_bit_cast(float, u & 0xFFFF0000u);
        const float lo = f[e] - hf;
        al[e] = (short)(__builtin_bit_cast(unsigned, lo) >> 16);
      }
      const bf16x8 bq = __builtin_bit_cast(bf16x8, e4[j2]);
      acc = __builtin_amdgcn_mfma_f32_16x16x32_bf16(ah, bq, acc, 0, 0, 0);
      acc = __builtin_amdgcn_mfma_f32_16x16x32_bf16(al, bq, acc, 0, 0, 0);
    }
  }

  // C/D layout (m89/R6-verified): col = lane&15, row = (lane>>4)*4 + reg
  #pragma unroll
  for (int r = 0; r < 4; ++r)
    T_lds[kg * 4 + r][wid * 16 + l15] = acc[r];
  __syncthreads();

  // --- dump T[16][64] coalesced to global scratch ---
  float* __restrict__ td = tdump + ((size_t)b * SL + row0) * 64;
  #pragma unroll
  for (int i = 0; i < 4; ++i) {
    const int idx = i * 256 + tid;
    td[idx] = T_lds[idx >> 6][idx & 63];
  }
}

// ---------------------------------------------------------------------------
// Kernel 2: per-batch bins. R10-verified counting sort of 1024 rows by p,
// then 8-deep pipelined register-run accumulation over tdump rows; LDS
// atomics only at run boundaries (~50 per thread-quarter).
// ---------------------------------------------------------------------------
__global__ __launch_bounds__(256) void reduce3(
    const float* __restrict__ tdump, const int* __restrict__ adds,
    float* __restrict__ g_part2) {
  __shared__ int   adds_s[SL];
  __shared__ int   orderR[SL];
  __shared__ int   cntR[NPOS], offm[NPOS];
  __shared__ float binL[NPOS * 64];    // 12.8 KB

  const int tid = threadIdx.x, b = blockIdx.x;
  ((int4*)adds_s)[tid] = ((const int4*)(adds + (size_t)b * SL))[tid];
  for (int k = tid; k < NPOS * 64; k += 256) binL[k] = 0.0f;
  if (tid < NPOS) cntR[tid] = 0;
  __syncthreads();
  for (int i = tid; i < SL; i += 256) atomicAdd(&cntR[adds_s[i]], 1);
  __syncthreads();
  if (tid == 0) {
    int run = 0;
    for (int c = 0; c < NPOS; ++c) { offm[c] = run; run += cntR[c]; }
  }
  __syncthreads();
  for (int i = tid; i < SL; i += 256)
    orderR[atomicAdd(&offm[adds_s[i]], 1)] = i;
  __syncthreads();

  const int q = tid & 63, qr = tid >> 6;        // wave-uniform quarter
  const float* __restrict__ td = tdump + (size_t)b * SL * 64;
  float s = 0.0f;
  int pcur = -1;
  for (int k0 = qr * 256; k0 < qr * 256 + 256; k0 += 8) {
    int rr[8]; float tv[8];
    #pragma unroll
    for (int u = 0; u < 8; ++u) rr[u] = orderR[k0 + u];
    #pragma unroll
    for (int u = 0; u < 8; ++u) tv[u] = td[(size_t)rr[u] * 64 + q];
    #pragma unroll
    for (int u = 0; u < 8; ++u) {
      const int p = adds_s[rr[u]];              // wave-uniform
      if (p != pcur) {
        if (pcur >= 0) atomicAdd(&binL[pcur * 64 + q], s);
        pcur = p; s = 0.0f;
      }
      s += tv[u];
    }
  }
  if (pcur >= 0) atomicAdd(&binL[pcur * 64 + q], s);
  __syncthreads();

  float* __restrict__ gp = g_part2 + (size_t)b * 3200;
  for (int k = tid; k < NPOS * 64; k += 256) gp[k] = binL[k];
}

// ---------------------------------------------------------------------------
// Kernel 3: g_hist[bin] = sum over 64 batches. Plain stores, no atomics.
// ---------------------------------------------------------------------------
__global__ __launch_bounds__(256) void reduce4(
    const float* __restrict__ g_part2, float* __restrict__ g_hist) {
  const int bin = blockIdx.x * 256 + threadIdx.x;
  if (bin >= NBINS) return;
  const int p = bin / NPOS, q = bin % NPOS;
  float s = 0.0f;
  #pragma unroll 8
  for (int bb = 0; bb < BZ; ++bb)
    s += g_part2[(size_t)bb * 3200 + p * 64 + q];
  g_hist[bin] = s;
}

// ---------------------------------------------------------------------------
// Kernel 4: out = s_arc + ALPHA * sigmoid(g_hist)[pos-pair bin].
// R16-verified: NT load + NT store, ~6.6 TB/s combined — unchanged.
// ---------------------------------------------------------------------------
__global__ __launch_bounds__(A_THREADS) void apply_kernel(
    const float* __restrict__ s, const int* __restrict__ pos,
    const float* __restrict__ g_hist, float* __restrict__ out) {
  __shared__ float sig[NBINS];
  __shared__ int   pos_s[SL];

  const int tid = threadIdx.x;
  const int b   = blockIdx.x / BLOCKS_PER_B;
  const int i0  = (blockIdx.x % BLOCKS_PER_B) * ROWS_PER_BLOCK;

  ((int4*)pos_s)[tid] = ((const int4*)(pos + (size_t)b * SL))[tid];
  for (int k = tid; k < NBINS; k += A_THREADS) {
    const float h = g_hist[k];
    sig[k] = 1.0f / (1.0f + __expf(-h));
  }
  __syncthreads();

  const int4 pj = ((const int4*)pos_s)[tid];
  const size_t rowoff = ((size_t)b * SL + i0) * SL;
  const f32x4* __restrict__ srow = (const f32x4*)(s + rowoff);
  f32x4* __restrict__ orow = (f32x4*)(out + rowoff);

  for (int r = 0; r < ROWS_PER_BLOCK; ++r) {
    const int base = pos_s[i0 + r] * NPOS;    // wave-uniform broadcast
    const f32x4 sv =
        __builtin_nontemporal_load(srow + (size_t)r * (SL / 4) + tid);
    f32x4 ov;
    ov[0] = sv[0] + ALPHA * sig[base + pj.x];
    ov[1] = sv[1] + ALPHA * sig[base + pj.y];
    ov[2] = sv[2] + ALPHA * sig[base + pj.z];
    ov[3] = sv[3] + ALPHA * sig[base + pj.w];
    __builtin_nontemporal_store(ov, orow + (size_t)r * (SL / 4) + tid);
  }
}

extern "C" void kernel_launch(void* const* d_in, const int* in_sizes, int n_in,
                              void* d_out, int out_size, void* d_ws, size_t ws_size,
                              hipStream_t stream) {
  const float* a_arc = (const float*)d_in[0];
  const float* s_arc = (const float*)d_in[1];
  const int*   adds  = (const int*)d_in[2];
  const int*   pos   = (const int*)d_in[3];
  float* out     = (float*)d_out;
  float* g_hist  = (float*)d_ws;                      // 2500 f
  float* g_part2 = g_hist + 8192;                     // 64 x 3200 f = 820 KB
  float* tdump   = g_hist + 1048576;                  // 4 MB off, 16.8 MB
  uint4* efrag   = (uint4*)(g_hist + 8388608);        // 32 MB off, 8.4 MB

  // No memset needed: every output buffer is fully overwritten with plain
  // stores each call (no global atomics anywhere).
  efrag_kernel<<<E_BLOCKS, E_THREADS, 0, stream>>>(adds, efrag);
  hist_mfma   <<<H_BLOCKS, H_THREADS, 0, stream>>>(a_arc, efrag, tdump);
  reduce3     <<<BZ, 256, 0, stream>>>(tdump, adds, g_part2);
  reduce4     <<<10, 256, 0, stream>>>(g_part2, g_hist);
  apply_kernel<<<A_BLOCKS, A_THREADS, 0, stream>>>(s_arc, pos, g_hist, out);
}

// Round 21
// 160.198 us; speedup vs baseline: 1.3313x; 1.3313x over previous
//
#include <hip/hip_runtime.h>

// Problem constants (fixed by setup_inputs):
//   a_arc, s_arc : [64, 1024, 1024] f32
//   adds, pos    : [64, 1024] int32 in [0, 50)
constexpr int NPOS  = 50;
constexpr int NBINS = NPOS * NPOS;   // 2500
constexpr int SL    = 1024;
constexpr int BZ    = 64;
constexpr float ALPHA = 0.3f;

using nat_f4 = __attribute__((ext_vector_type(4))) float;   // NT-loadable

// ---------------- hist (row-gather) config ----------------
constexpr int NRNG      = 8;                   // p-ranges {7,7,6,6,6,6,6,6}
constexpr int NHALF     = 2;                   // row halves
constexpr int PSLICE    = 352;                 // per-block output slice (floats)
constexpr int LISTCAP   = 520;                 // max rows per (range, half)
constexpr int H_THREADS = 256;                 // thread t owns cols 4t..4t+3
constexpr int H_BLOCKS  = BZ * NRNG * NHALF;   // 1024 -> 4 resident/CU

__device__ __forceinline__ int rng_lo(int r) { return r < 2 ? 7 * r : 14 + 6 * (r - 2); }
__device__ __forceinline__ int rng_sz(int r) { return r < 2 ? 7 : 6; }

// g_meta layout per batch (stride 4096 ints):
//   [0,1024)        order2 (cols sorted by q)
//   [1024,1074)     cntQ
//   [1074,1124)     offQs
//   [1124,1226)     offP[half][p], 51 entries per half ([50] = 512)
//   [2048,2560)     orderH half 0: (p<<12)|row, rows sorted by p
//   [2560,3072)     orderH half 1
constexpr int META_STRIDE = 4096;

// ---------------- reduce2 / apply config ----------------
constexpr int R2_THREADS = 256;
constexpr int R2_BLOCKS  = (NBINS + R2_THREADS - 1) / R2_THREADS;  // 10
constexpr int A_THREADS      = 256;
constexpr int ROWS_PER_BLOCK = 32;
constexpr int BLOCKS_PER_B   = SL / ROWS_PER_BLOCK;   // 32
constexpr int A_BLOCKS       = BZ * BLOCKS_PER_B;     // 2048

// ---------------------------------------------------------------------------
// Kernel 0: per-batch sort setup — hoists R16's per-block prologue (q-sort of
// all cols, p-sort of rows per half) out of the 1024 hist blocks.
// ---------------------------------------------------------------------------
__global__ __launch_bounds__(256) void setup_kernel(
    const int* __restrict__ adds, int* __restrict__ g_meta) {
  __shared__ int adds_s[SL];
  __shared__ int cntQ[NPOS], offQ[NPOS], offQm[NPOS];
  __shared__ int cntP[2][NPOS], offP[2][NPOS], offPm[2][NPOS];

  const int tid = threadIdx.x, b = blockIdx.x;
  ((int4*)adds_s)[tid] = ((const int4*)(adds + (size_t)b * SL))[tid];
  if (tid < NPOS) { cntQ[tid] = 0; cntP[0][tid] = 0; cntP[1][tid] = 0; }
  __syncthreads();

  for (int i = tid; i < SL; i += 256) {
    const int p = adds_s[i];
    atomicAdd(&cntQ[p], 1);
    atomicAdd(&cntP[i >> 9][p], 1);
  }
  __syncthreads();
  if (tid == 0) {              // three concurrent serial prefixes (one/wave)
    int run = 0;
    for (int c = 0; c < NPOS; ++c) { offQ[c] = run; offQm[c] = run; run += cntQ[c]; }
  } else if (tid == 64) {
    int run = 0;
    for (int c = 0; c < NPOS; ++c) { offP[0][c] = run; offPm[0][c] = run; run += cntP[0][c]; }
  } else if (tid == 128) {
    int run = 0;
    for (int c = 0; c < NPOS; ++c) { offP[1][c] = run; offPm[1][c] = run; run += cntP[1][c]; }
  }
  __syncthreads();

  int* __restrict__ gm = g_meta + (size_t)b * META_STRIDE;
  for (int i = tid; i < SL; i += 256) {
    const int p = adds_s[i], h = i >> 9;
    gm[atomicAdd(&offQm[p], 1)] = i;                           // order2
    gm[2048 + h * 512 + atomicAdd(&offPm[h][p], 1)] = (p << 12) | i;  // orderH
  }
  if (tid < NPOS) {
    gm[1024 + tid] = cntQ[tid];
    gm[1074 + tid] = offQ[tid];
    gm[1124 + tid] = offP[0][tid];
    gm[1175 + tid] = offP[1][tid];
  }
  if (tid == 0) { gm[1124 + 50] = 512; gm[1175 + 50] = 512; }
}

// ---------------------------------------------------------------------------
// Kernel 1: R16's verified NT gather hist with the prologue REMOVED (lists
// and sorts preloaded from g_meta). LDS 43->38.5 KB => 4 resident blocks/CU;
// 1024 blocks => backfill for binomial stragglers. Main loop & col-reduce
// epilogue byte-identical to the 156.3us R16 kernel.
// ---------------------------------------------------------------------------
__global__ __launch_bounds__(H_THREADS) void hist_gather(
    const float* __restrict__ a, const int* __restrict__ g_meta,
    float* __restrict__ g_part) {
  __shared__ float accL[8][SL];         // 32 KB: [p_loc][col]; slot 7 = dummy
  __shared__ int   list[LISTCAP];       // 2 KB: (pl<<12)|row, sorted by pl
  __shared__ int   order2[SL];          // 4 KB: cols sorted by q
  __shared__ int   cntQ[NPOS], offQs[NPOS];

  const int tid  = threadIdx.x;
  const int b    = blockIdx.x / (NRNG * NHALF);
  const int rem  = blockIdx.x % (NRNG * NHALF);
  const int rg   = rem >> 1;
  const int half = rem & 1;
  const int lo   = rng_lo(rg), sz = rng_sz(rg);

  const int* __restrict__ gm = g_meta + (size_t)b * META_STRIDE;
  const int s0 = gm[1124 + half * 51 + lo];          // uniform scalar reads
  const int s1 = gm[1124 + half * 51 + lo + sz];
  const int N  = s1 - s0;

  // --- preload: list slice (rebased tags), order2, cntQ/offQs; zero accL ---
  ((int4*)order2)[tid] = ((const int4*)gm)[tid];     // 1024 ints
  if (tid < NPOS) { cntQ[tid] = gm[1024 + tid]; offQs[tid] = gm[1074 + tid]; }
  for (int i = tid; i < N; i += H_THREADS)
    list[i] = gm[2048 + half * 512 + s0 + i] - (lo << 12);
  #pragma unroll
  for (int p = 0; p < 8; ++p) ((float4*)&accL[p][0])[tid] = float4{0, 0, 0, 0};
  __syncthreads();
  const int Npad = (N + 7) & ~7;
  if (tid < 8 && N + tid < Npad)        // pad: sentinel p_loc=7, valid row
    list[N + tid] = (7 << 12) | (N > 0 ? (list[N - 1] & 0xFFF) : 0);
  __syncthreads();

  // --- main loop: stream sorted rows, 8-deep ping-pong, NT 4-KB rows ---
  const nat_f4* __restrict__ Ab = (const nat_f4*)(a + (size_t)b * SL * SL);
  float4 creg = {0, 0, 0, 0};
  int pcur = 7;

  int    eA[8], eB[8];
  nat_f4 vA[8], vB[8];
  auto loadbank = [&](int (&e)[8], nat_f4 (&v)[8], int k) {
    #pragma unroll
    for (int u = 0; u < 8; ++u) {
      e[u] = __builtin_amdgcn_readfirstlane(list[k + u]);  // uniform -> SGPR
      v[u] = __builtin_nontemporal_load(
          Ab + (size_t)(e[u] & 0xFFF) * (SL / 4) + tid);   // NT 1 KB/wave-instr
    }
  };
  auto procbank = [&](int (&e)[8], nat_f4 (&v)[8]) {
    #pragma unroll
    for (int u = 0; u < 8; ++u) {
      const int pl = e[u] >> 12;
      if (pl != pcur) {                 // block-uniform scalar branch
        ((float4*)&accL[pcur][0])[tid] = creg;   // one store per p-run
        creg = float4{0, 0, 0, 0};
        pcur = pl;
      }
      creg.x += v[u][0]; creg.y += v[u][1]; creg.z += v[u][2]; creg.w += v[u][3];
    }
  };

  if (Npad > 0) {
    pcur = list[0] >> 12;
    loadbank(eA, vA, 0);
    for (int k = 0; k < Npad; k += 16) {
      if (k + 8 < Npad) loadbank(eB, vB, k + 8);
      procbank(eA, vA);
      if (k + 16 < Npad) loadbank(eA, vA, k + 16);
      if (k + 8 < Npad) procbank(eB, vB);
    }
    ((float4*)&accL[pcur][0])[tid] = creg;       // final flush (7 = dummy ok)
  }
  __syncthreads();

  // --- col reduce: slice[pl*50+q] = sum_{cols j: adds[j]==q} accL[pl][j] ---
  float* __restrict__ gp = g_part + (size_t)blockIdx.x * PSLICE;
  for (int bin = tid; bin < sz * NPOS; bin += H_THREADS) {
    const int pl = bin / NPOS, q = bin % NPOS;
    const int q0 = offQs[q], n = cntQ[q];
    float s = 0.0f;
    for (int k2 = 0; k2 < n; ++k2) s += accL[pl][order2[q0 + k2]];
    gp[bin] = s;                        // plain store, private slice
  }
}

// ---------------------------------------------------------------------------
// Kernel 1.5: g_hist[bin] = sum over 64 batches x 2 halves of that bin's
// range-slice. Plain stores; one thread per bin -> no atomics, no memset.
// ---------------------------------------------------------------------------
__global__ __launch_bounds__(R2_THREADS) void reduce2(
    const float* __restrict__ g_part, float* __restrict__ g_hist) {
  const int bin = blockIdx.x * R2_THREADS + threadIdx.x;
  if (bin >= NBINS) return;
  const int p = bin / NPOS, q = bin % NPOS;
  const int rg = (p < 14) ? p / 7 : 2 + (p - 14) / 6;
  const int pl = (p < 14) ? p % 7 : (p - 14) % 6;
  const float* __restrict__ base =
      g_part + (size_t)(rg * NHALF) * PSLICE + pl * NPOS + q;
  float s = 0.0f;
  #pragma unroll 8
  for (int bb = 0; bb < BZ; ++bb) {
    const size_t o = (size_t)bb * (NRNG * NHALF) * PSLICE;
    s += base[o] + base[o + PSLICE];
  }
  g_hist[bin] = s;
}

// ---------------------------------------------------------------------------
// Kernel 2: out = s_arc + ALPHA * sigmoid(g_hist)[pos-pair bin].
// R16-verified: NT load of s_arc + NT store of out; ~6.6 TB/s combined.
// ---------------------------------------------------------------------------
__global__ __launch_bounds__(A_THREADS) void apply_kernel(
    const float* __restrict__ s, const int* __restrict__ pos,
    const float* __restrict__ g_hist, float* __restrict__ out) {
  __shared__ float sig[NBINS];
  __shared__ int   pos_s[SL];

  const int tid = threadIdx.x;
  const int b   = blockIdx.x / BLOCKS_PER_B;
  const int i0  = (blockIdx.x % BLOCKS_PER_B) * ROWS_PER_BLOCK;

  ((int4*)pos_s)[tid] = ((const int4*)(pos + (size_t)b * SL))[tid];
  for (int k = tid; k < NBINS; k += A_THREADS) {
    const float h = g_hist[k];
    sig[k] = 1.0f / (1.0f + __expf(-h));
  }
  __syncthreads();

  const int4 pj = ((const int4*)pos_s)[tid];
  const size_t rowoff = ((size_t)b * SL + i0) * SL;
  const nat_f4* __restrict__ srow = (const nat_f4*)(s + rowoff);
  nat_f4* __restrict__ orow = (nat_f4*)(out + rowoff);

  for (int r = 0; r < ROWS_PER_BLOCK; ++r) {
    const int base = pos_s[i0 + r] * NPOS;    // wave-uniform broadcast
    const nat_f4 sv =
        __builtin_nontemporal_load(srow + (size_t)r * (SL / 4) + tid);
    nat_f4 ov;
    ov[0] = sv[0] + ALPHA * sig[base + pj.x];
    ov[1] = sv[1] + ALPHA * sig[base + pj.y];
    ov[2] = sv[2] + ALPHA * sig[base + pj.z];
    ov[3] = sv[3] + ALPHA * sig[base + pj.w];
    __builtin_nontemporal_store(ov, orow + (size_t)r * (SL / 4) + tid);
  }
}

extern "C" void kernel_launch(void* const* d_in, const int* in_sizes, int n_in,
                              void* d_out, int out_size, void* d_ws, size_t ws_size,
                              hipStream_t stream) {
  const float* a_arc = (const float*)d_in[0];
  const float* s_arc = (const float*)d_in[1];
  const int*   adds  = (const int*)d_in[2];
  const int*   pos   = (const int*)d_in[3];
  float* out    = (float*)d_out;
  float* g_hist = (float*)d_ws;                     // 2500 floats
  int*   g_meta = (int*)(g_hist + 4096);            // 64 x 4096 ints = 1 MB
  float* g_part = (float*)(g_meta + BZ * META_STRIDE);  // 1024 x 352 f = 1.4 MB

  // No memset needed: g_meta/g_part/g_hist are fully overwritten with plain
  // stores every call (no global atomics anywhere).
  setup_kernel<<<BZ, 256, 0, stream>>>(adds, g_meta);
  hist_gather <<<H_BLOCKS, H_THREADS, 0, stream>>>(a_arc, g_meta, g_part);
  reduce2     <<<R2_BLOCKS, R2_THREADS, 0, stream>>>(g_part, g_hist);
  apply_kernel<<<A_BLOCKS, A_THREADS, 0, stream>>>(s_arc, pos, g_hist, out);
}

// Round 22
// 154.274 us; speedup vs baseline: 1.3825x; 1.0384x over previous
//
#include <hip/hip_runtime.h>

// Problem constants (fixed by setup_inputs):
//   a_arc, s_arc : [64, 1024, 1024] f32
//   adds, pos    : [64, 1024] int32 in [0, 50)
constexpr int NPOS  = 50;
constexpr int NBINS = NPOS * NPOS;   // 2500
constexpr int SL    = 1024;
constexpr int BZ    = 64;
constexpr float ALPHA = 0.3f;

using nat_f4 = __attribute__((ext_vector_type(4))) float;   // NT-loadable

// ---------------- hist (row-gather) config — R16 verbatim (best: 156.3us) --
constexpr int NRNG      = 8;
constexpr int PSLICE    = 352;                 // per-block output slice (floats)
constexpr int H_THREADS = 256;                 // thread t owns cols 4t..4t+3
constexpr int H_BLOCKS  = BZ * NRNG;           // 512

__device__ __forceinline__ int rng_lo(int r) { return r < 2 ? 7 * r : 14 + 6 * (r - 2); }
__device__ __forceinline__ int rng_sz(int r) { return r < 2 ? 7 : 6; }

// ---------------- reduce2 / apply config ----------------
constexpr int R2_THREADS = 256;
constexpr int R2_BLOCKS  = (NBINS + R2_THREADS - 1) / R2_THREADS;  // 10
constexpr int A_THREADS      = 256;
constexpr int ROWS_PER_BLOCK = 32;
constexpr int BLOCKS_PER_B   = SL / ROWS_PER_BLOCK;   // 32
constexpr int A_BLOCKS       = BZ * BLOCKS_PER_B;     // 2048

// ---------------------------------------------------------------------------
// Kernel 1: NT-load gather hist (R16-verified). Counting-sorted row list,
// 8-deep ping-pong, NT 4-KB full-row loads (1 KB/wave-instr), register
// run-accumulation, one plain LDS store per p-run, q-sorted col-reduce,
// plain stores to private slices. ~72us @ ~3.7 TB/s gather-read — measured
// invariant across occupancy 2-4 blocks/CU (R17/R21) and structures (R3-R18).
// ---------------------------------------------------------------------------
__global__ __launch_bounds__(H_THREADS) void hist_gather(
    const float* __restrict__ a, const int* __restrict__ adds,
    float* __restrict__ g_part) {
  __shared__ int   adds_s[SL];          // 4 KB
  __shared__ float accL[8][SL];         // 32 KB: [p_loc][col]; slot 7 = dummy
  __shared__ int   list[SL + 8];        // 4 KB: (p_loc<<12)|row, sorted by p
  __shared__ int   order2[SL];          // 4 KB: cols sorted by q
  __shared__ int   cnt8[8], off8[8];
  __shared__ int   cntQ[NPOS], offQs[NPOS], offQm[NPOS];
  __shared__ int   nrows_s;

  const int tid = threadIdx.x;
  const int b   = blockIdx.x / NRNG;
  const int rg  = blockIdx.x % NRNG;
  const int lo  = rng_lo(rg), sz = rng_sz(rg);

  ((int4*)adds_s)[tid] = ((const int4*)(adds + (size_t)b * SL))[tid];
  #pragma unroll
  for (int p = 0; p < 8; ++p) ((float4*)&accL[p][0])[tid] = float4{0, 0, 0, 0};
  if (tid < 8) cnt8[tid] = 0;
  if (tid < NPOS) cntQ[tid] = 0;
  __syncthreads();

  // --- counting sorts: range-rows by p_loc, all cols by q (verified) ---
  for (int i = tid; i < SL; i += H_THREADS) {
    const int p = adds_s[i];
    const int pl = p - lo;
    if ((unsigned)pl < (unsigned)sz) atomicAdd(&cnt8[pl], 1);
    atomicAdd(&cntQ[p], 1);
  }
  __syncthreads();
  if (tid == 0) {                       // wave 0: row prefix
    int run = 0;
    #pragma unroll
    for (int c = 0; c < 8; ++c) { off8[c] = run; run += cnt8[c]; }
    nrows_s = run;
  } else if (tid == 64) {               // wave 1: col prefix, concurrent
    int run = 0;
    for (int c = 0; c < NPOS; ++c) { offQs[c] = run; offQm[c] = run; run += cntQ[c]; }
  }
  __syncthreads();
  for (int i = tid; i < SL; i += H_THREADS) {
    const int p = adds_s[i];
    const int pl = p - lo;
    if ((unsigned)pl < (unsigned)sz)
      list[atomicAdd(&off8[pl], 1)] = (pl << 12) | i;
    order2[atomicAdd(&offQm[p], 1)] = i;
  }
  __syncthreads();
  const int N    = nrows_s;
  const int Npad = (N + 7) & ~7;
  if (tid < 8 && N + tid < Npad)        // pad: sentinel p_loc=7, valid row
    list[N + tid] = (7 << 12) | (N > 0 ? (list[N - 1] & 0xFFF) : 0);
  __syncthreads();

  // --- main loop: stream sorted rows, 8-deep ping-pong, 4-KB-granular ---
  const nat_f4* __restrict__ Ab = (const nat_f4*)(a + (size_t)b * SL * SL);
  float4 creg = {0, 0, 0, 0};
  int pcur = 7;

  int    eA[8], eB[8];
  nat_f4 vA[8], vB[8];
  auto loadbank = [&](int (&e)[8], nat_f4 (&v)[8], int k) {
    #pragma unroll
    for (int u = 0; u < 8; ++u) {
      e[u] = __builtin_amdgcn_readfirstlane(list[k + u]);  // uniform -> SGPR
      v[u] = __builtin_nontemporal_load(
          Ab + (size_t)(e[u] & 0xFFF) * (SL / 4) + tid);   // NT 1 KB/wave-instr
    }
  };
  auto procbank = [&](int (&e)[8], nat_f4 (&v)[8]) {
    #pragma unroll
    for (int u = 0; u < 8; ++u) {
      const int pl = e[u] >> 12;
      if (pl != pcur) {                 // block-uniform scalar branch
        ((float4*)&accL[pcur][0])[tid] = creg;   // one store per p-run
        creg = float4{0, 0, 0, 0};
        pcur = pl;
      }
      creg.x += v[u][0]; creg.y += v[u][1]; creg.z += v[u][2]; creg.w += v[u][3];
    }
  };

  if (Npad > 0) {
    pcur = list[0] >> 12;
    loadbank(eA, vA, 0);
    for (int k = 0; k < Npad; k += 16) {
      if (k + 8 < Npad) loadbank(eB, vB, k + 8);
      procbank(eA, vA);
      if (k + 16 < Npad) loadbank(eA, vA, k + 16);
      if (k + 8 < Npad) procbank(eB, vB);
    }
    ((float4*)&accL[pcur][0])[tid] = creg;       // final flush (7 = dummy ok)
  }
  __syncthreads();

  // --- col reduce: slice[pl*50+q] = sum_{cols j: adds[j]==q} accL[pl][j] ---
  float* __restrict__ gp = g_part + (size_t)blockIdx.x * PSLICE;
  for (int bin = tid; bin < sz * NPOS; bin += H_THREADS) {
    const int pl = bin / NPOS, q = bin % NPOS;
    const int s0 = offQs[q], n = cntQ[q];
    float s = 0.0f;
    for (int k2 = 0; k2 < n; ++k2) s += accL[pl][order2[s0 + k2]];
    gp[bin] = s;                        // plain store, private slice
  }
}

// ---------------------------------------------------------------------------
// Kernel 1.5: g_hist[bin] = sum over 64 batches of that bin's range-slice.
// Plain stores; each bin owned by one thread -> no atomics, no memset.
// ---------------------------------------------------------------------------
__global__ __launch_bounds__(R2_THREADS) void reduce2(
    const float* __restrict__ g_part, float* __restrict__ g_hist) {
  const int bin = blockIdx.x * R2_THREADS + threadIdx.x;
  if (bin >= NBINS) return;
  const int p = bin / NPOS, q = bin % NPOS;
  const int rg = (p < 14) ? p / 7 : 2 + (p - 14) / 6;
  const int pl = (p < 14) ? p % 7 : (p - 14) % 6;
  float s = 0.0f;
  #pragma unroll 8
  for (int bb = 0; bb < BZ; ++bb)
    s += g_part[(size_t)(bb * NRNG + rg) * PSLICE + pl * NPOS + q];
  g_hist[bin] = s;
}

// ---------------------------------------------------------------------------
// Kernel 2: out = s_arc + ALPHA * sigmoid(g_hist)[pos-pair bin].
// R16-verified: NT load of s_arc + NT store of out; ~6.6 TB/s combined.
// ---------------------------------------------------------------------------
__global__ __launch_bounds__(A_THREADS) void apply_kernel(
    const float* __restrict__ s, const int* __restrict__ pos,
    const float* __restrict__ g_hist, float* __restrict__ out) {
  __shared__ float sig[NBINS];
  __shared__ int   pos_s[SL];

  const int tid = threadIdx.x;
  const int b   = blockIdx.x / BLOCKS_PER_B;
  const int i0  = (blockIdx.x % BLOCKS_PER_B) * ROWS_PER_BLOCK;

  ((int4*)pos_s)[tid] = ((const int4*)(pos + (size_t)b * SL))[tid];
  for (int k = tid; k < NBINS; k += A_THREADS) {
    const float h = g_hist[k];
    sig[k] = 1.0f / (1.0f + __expf(-h));
  }
  __syncthreads();

  const int4 pj = ((const int4*)pos_s)[tid];
  const size_t rowoff = ((size_t)b * SL + i0) * SL;
  const nat_f4* __restrict__ srow = (const nat_f4*)(s + rowoff);
  nat_f4* __restrict__ orow = (nat_f4*)(out + rowoff);

  for (int r = 0; r < ROWS_PER_BLOCK; ++r) {
    const int base = pos_s[i0 + r] * NPOS;    // wave-uniform broadcast
    const nat_f4 sv =
        __builtin_nontemporal_load(srow + (size_t)r * (SL / 4) + tid);
    nat_f4 ov;
    ov[0] = sv[0] + ALPHA * sig[base + pj.x];
    ov[1] = sv[1] + ALPHA * sig[base + pj.y];
    ov[2] = sv[2] + ALPHA * sig[base + pj.z];
    ov[3] = sv[3] + ALPHA * sig[base + pj.w];
    __builtin_nontemporal_store(ov, orow + (size_t)r * (SL / 4) + tid);
  }
}

extern "C" void kernel_launch(void* const* d_in, const int* in_sizes, int n_in,
                              void* d_out, int out_size, void* d_ws, size_t ws_size,
                              hipStream_t stream) {
  const float* a_arc = (const float*)d_in[0];
  const float* s_arc = (const float*)d_in[1];
  const int*   adds  = (const int*)d_in[2];
  const int*   pos   = (const int*)d_in[3];
  float* out    = (float*)d_out;
  float* g_hist = (float*)d_ws;                 // 2500 floats
  float* g_part = g_hist + 4096;                // 512 x 352 floats = 0.72 MB

  // No memset needed: g_part slices and g_hist are fully overwritten with
  // plain stores every call (no atomic accumulation anywhere).
  hist_gather <<<H_BLOCKS, H_THREADS, 0, stream>>>(a_arc, adds, g_part);
  reduce2     <<<R2_BLOCKS, R2_THREADS, 0, stream>>>(g_part, g_hist);
  apply_kernel<<<A_BLOCKS, A_THREADS, 0, stream>>>(s_arc, pos, g_hist, out);
}